// Round 1
// baseline (96.589 us; speedup 1.0000x reference)
//
#include <hip/hip_runtime.h>

#define H 1024
#define S 2048
#define B 32

// Kernel A: v[b,h] = sum_o hidden[b,o] * W[o,h]
// grid = (H/256 h-tiles, B), block = 256. W is L2-resident (4 MB);
// hidden[b,o] is wave-uniform -> scalar loads.
__global__ __launch_bounds__(256) void proj_hidden_kernel(
    const float* __restrict__ hidden, const float* __restrict__ W,
    float* __restrict__ v)
{
    const int b = blockIdx.y;
    const int h = blockIdx.x * 256 + threadIdx.x;
    const float* hrow = hidden + b * H;
    float acc = 0.f;
#pragma unroll 8
    for (int o = 0; o < H; ++o) {
        acc += hrow[o] * W[(size_t)o * H + h];
    }
    v[b * H + h] = acc;
}

// Kernel B: energies[b,s] = dot(enc[s,b,:], v[b,:])
// One wave per row, 16 rows per wave. v cached in 16 VGPRs per lane.
// enc element offset for lane l, chunk k: k*256 + l*4  (float4, coalesced 1KB/instr)
__global__ __launch_bounds__(256) void energies_kernel(
    const float* __restrict__ enc, const float* __restrict__ v,
    float* __restrict__ e)
{
    const int lane = threadIdx.x & 63;
    const int wave = threadIdx.x >> 6;
    const int b = blockIdx.y;
    const int s_base = blockIdx.x * 64 + wave * 16;

    const float4* v4 = reinterpret_cast<const float4*>(v + b * H);
    float4 vr[4];
#pragma unroll
    for (int k = 0; k < 4; ++k) vr[k] = v4[k * 64 + lane];

#pragma unroll 4
    for (int r = 0; r < 16; ++r) {
        const int s = s_base + r;
        const float4* e4 = reinterpret_cast<const float4*>(
            enc + ((size_t)s * B + b) * H);
        float acc = 0.f;
#pragma unroll
        for (int k = 0; k < 4; ++k) {
            float4 x = e4[k * 64 + lane];
            acc += x.x * vr[k].x + x.y * vr[k].y + x.z * vr[k].z + x.w * vr[k].w;
        }
#pragma unroll
        for (int off = 32; off > 0; off >>= 1)
            acc += __shfl_down(acc, off, 64);
        if (lane == 0) e[b * S + s] = acc;
    }
}

// Kernel C: softmax over s per b. One block per b, 256 threads x 8 vals.
__global__ __launch_bounds__(256) void softmax_kernel(
    const float* __restrict__ e, float* __restrict__ out)
{
    const int b = blockIdx.x;
    const int tid = threadIdx.x;
    const int lane = tid & 63, wv = tid >> 6;

    float vals[8];
#pragma unroll
    for (int i = 0; i < 8; ++i) vals[i] = e[b * S + tid + i * 256];

    float m = vals[0];
#pragma unroll
    for (int i = 1; i < 8; ++i) m = fmaxf(m, vals[i]);
#pragma unroll
    for (int off = 32; off > 0; off >>= 1)
        m = fmaxf(m, __shfl_xor(m, off, 64));

    __shared__ float redm[4];
    __shared__ float reds[4];
    if (lane == 0) redm[wv] = m;
    __syncthreads();
    m = fmaxf(fmaxf(redm[0], redm[1]), fmaxf(redm[2], redm[3]));

    float sum = 0.f;
#pragma unroll
    for (int i = 0; i < 8; ++i) { vals[i] = __expf(vals[i] - m); sum += vals[i]; }
#pragma unroll
    for (int off = 32; off > 0; off >>= 1)
        sum += __shfl_xor(sum, off, 64);
    if (lane == 0) reds[wv] = sum;
    __syncthreads();
    sum = reds[0] + reds[1] + reds[2] + reds[3];

    const float inv = 1.f / sum;
#pragma unroll
    for (int i = 0; i < 8; ++i) out[b * S + tid + i * 256] = vals[i] * inv;
}

extern "C" void kernel_launch(void* const* d_in, const int* in_sizes, int n_in,
                              void* d_out, int out_size, void* d_ws, size_t ws_size,
                              hipStream_t stream) {
    const float* hidden = (const float*)d_in[0];   // [1,B,H]
    const float* enc    = (const float*)d_in[1];   // [S,B,H]
    const float* W      = (const float*)d_in[2];   // [H,H] (o,h)
    // d_in[3] is the bias: identically zero AND softmax-shift-invariant -> skipped.
    float* out = (float*)d_out;                    // [B,1,S]

    float* v = (float*)d_ws;                       // B*H floats   = 128 KB
    float* e = v + B * H;                          // B*S floats   = 256 KB

    proj_hidden_kernel<<<dim3(H / 256, B), 256, 0, stream>>>(hidden, W, v);
    energies_kernel<<<dim3(S / 64, B), 256, 0, stream>>>(enc, v, e);
    softmax_kernel<<<B, 256, 0, stream>>>(e, out);
}

// Round 2
// 58.854 us; speedup vs baseline: 1.6412x; 1.6412x over previous
//
#include <hip/hip_runtime.h>

#define H 1024
#define S 2048
#define B 32

// Kernel A: v[b,h] = sum_o hidden[b,o] * W[o,h]
// grid (H/256, B), block 1024. tx = h-quad (float4), ty = o-chunk of 64.
// W loads are dwordx4 coalesced; per-thread only 64 loads -> latency hidden.
__global__ __launch_bounds__(1024) void proj_hidden_kernel(
    const float* __restrict__ hidden, const float* __restrict__ W,
    float* __restrict__ v)
{
    const int b  = blockIdx.y;
    const int tx = threadIdx.x & 63;     // float4 column slot
    const int ty = threadIdx.x >> 6;     // o-chunk 0..15
    const int h4 = blockIdx.x * 64 + tx; // float4 col index in [0,256)
    const float4* W4 = reinterpret_cast<const float4*>(W);
    const float* hrow = hidden + b * H;

    float4 acc = {0.f, 0.f, 0.f, 0.f};
#pragma unroll 8
    for (int i = 0; i < 64; ++i) {
        const int o = ty * 64 + i;               // wave-uniform
        const float hs = hrow[o];                // broadcast load
        const float4 w = W4[(size_t)o * (H / 4) + h4];
        acc.x += hs * w.x; acc.y += hs * w.y;
        acc.z += hs * w.z; acc.w += hs * w.w;
    }

    __shared__ float4 red[16][64];
    red[ty][tx] = acc;
    __syncthreads();
#pragma unroll
    for (int step = 8; step >= 1; step >>= 1) {
        if (ty < step) {
            const float4 o2 = red[ty + step][tx];
            acc.x += o2.x; acc.y += o2.y; acc.z += o2.z; acc.w += o2.w;
            red[ty][tx] = acc;
        }
        __syncthreads();
    }
    if (ty == 0)
        reinterpret_cast<float4*>(v + b * H)[h4] = acc;
}

// Kernel B: energies[b,s] = dot(enc[s,b,:], v[b,:])
// One wave per 16 rows. Per-lane partials for all 16 rows, then a
// 17-shuffle merge-tree (vs 96 serial shuffles): after xor 1,2,4,8 the
// value in each lane is the 16-lane-group sum of row (lane&15); xor 16,32
// finish the cross-group sum. Lanes 0..15 store rows 0..15.
__global__ __launch_bounds__(256) void energies_kernel(
    const float* __restrict__ enc, const float* __restrict__ v,
    float* __restrict__ e)
{
    const int lane = threadIdx.x & 63;
    const int wave = threadIdx.x >> 6;
    const int b = blockIdx.y;
    const int s_base = blockIdx.x * 64 + wave * 16;

    const float4* v4 = reinterpret_cast<const float4*>(v + b * H);
    float4 vr[4];
#pragma unroll
    for (int k = 0; k < 4; ++k) vr[k] = v4[k * 64 + lane];

    float acc[16];
#pragma unroll
    for (int r = 0; r < 16; ++r) {
        const float4* e4 = reinterpret_cast<const float4*>(
            enc + ((size_t)(s_base + r) * B + b) * H);
        float a = 0.f;
#pragma unroll
        for (int k = 0; k < 4; ++k) {
            const float4 x = e4[k * 64 + lane];
            a += x.x * vr[k].x + x.y * vr[k].y + x.z * vr[k].z + x.w * vr[k].w;
        }
        acc[r] = a;
    }

    float t[8];
#pragma unroll
    for (int j = 0; j < 8; ++j) {            // xor 1: 16 -> 8
        const float a = acc[2 * j], c = acc[2 * j + 1];
        const float send = (lane & 1) ? a : c;
        const float recv = __shfl_xor(send, 1, 64);
        t[j] = ((lane & 1) ? c : a) + recv;
    }
#pragma unroll
    for (int j = 0; j < 4; ++j) {            // xor 2: 8 -> 4
        const float a = t[2 * j], c = t[2 * j + 1];
        const float send = (lane & 2) ? a : c;
        const float recv = __shfl_xor(send, 2, 64);
        t[j] = ((lane & 2) ? c : a) + recv;
    }
#pragma unroll
    for (int j = 0; j < 2; ++j) {            // xor 4: 4 -> 2
        const float a = t[2 * j], c = t[2 * j + 1];
        const float send = (lane & 4) ? a : c;
        const float recv = __shfl_xor(send, 4, 64);
        t[j] = ((lane & 4) ? c : a) + recv;
    }
    {                                        // xor 8: 2 -> 1
        const float a = t[0], c = t[1];
        const float send = (lane & 8) ? a : c;
        const float recv = __shfl_xor(send, 8, 64);
        t[0] = ((lane & 8) ? c : a) + recv;
    }
    t[0] += __shfl_xor(t[0], 16, 64);
    t[0] += __shfl_xor(t[0], 32, 64);

    if (lane < 16)
        e[b * S + s_base + lane] = t[0];
}

// Kernel C: softmax over s per b. One block per b, 256 threads x 8 vals.
__global__ __launch_bounds__(256) void softmax_kernel(
    const float* __restrict__ e, float* __restrict__ out)
{
    const int b = blockIdx.x;
    const int tid = threadIdx.x;
    const int lane = tid & 63, wv = tid >> 6;

    float vals[8];
#pragma unroll
    for (int i = 0; i < 8; ++i) vals[i] = e[b * S + tid + i * 256];

    float m = vals[0];
#pragma unroll
    for (int i = 1; i < 8; ++i) m = fmaxf(m, vals[i]);
#pragma unroll
    for (int off = 32; off > 0; off >>= 1)
        m = fmaxf(m, __shfl_xor(m, off, 64));

    __shared__ float redm[4];
    __shared__ float reds[4];
    if (lane == 0) redm[wv] = m;
    __syncthreads();
    m = fmaxf(fmaxf(redm[0], redm[1]), fmaxf(redm[2], redm[3]));

    float sum = 0.f;
#pragma unroll
    for (int i = 0; i < 8; ++i) { vals[i] = __expf(vals[i] - m); sum += vals[i]; }
#pragma unroll
    for (int off = 32; off > 0; off >>= 1)
        sum += __shfl_xor(sum, off, 64);
    if (lane == 0) reds[wv] = sum;
    __syncthreads();
    sum = reds[0] + reds[1] + reds[2] + reds[3];

    const float inv = 1.f / sum;
#pragma unroll
    for (int i = 0; i < 8; ++i) out[b * S + tid + i * 256] = vals[i] * inv;
}

extern "C" void kernel_launch(void* const* d_in, const int* in_sizes, int n_in,
                              void* d_out, int out_size, void* d_ws, size_t ws_size,
                              hipStream_t stream) {
    const float* hidden = (const float*)d_in[0];   // [1,B,H]
    const float* enc    = (const float*)d_in[1];   // [S,B,H]
    const float* W      = (const float*)d_in[2];   // [H,H] (o,h)
    // d_in[3] bias: identically zero AND softmax-shift-invariant -> skipped.
    float* out = (float*)d_out;                    // [B,1,S]

    float* v = (float*)d_ws;                       // B*H floats = 128 KB
    float* e = v + B * H;                          // B*S floats = 256 KB

    proj_hidden_kernel<<<dim3(H / 256, B), 1024, 0, stream>>>(hidden, W, v);
    energies_kernel<<<dim3(S / 64, B), 256, 0, stream>>>(enc, v, e);
    softmax_kernel<<<B, 256, 0, stream>>>(e, out);
}

// Round 3
// 53.671 us; speedup vs baseline: 1.7996x; 1.0966x over previous
//
#include <hip/hip_runtime.h>

#define H 1024
#define S 2048
#define B 32

typedef float f4 __attribute__((ext_vector_type(4)));

// Kernel A: v[b,h] = sum_o hidden[b,o] * W[o,h], 2 b's per block.
// grid (16,16) = 256 blocks x 1024 threads. tx = quad (16/block), ty = o-chunk
// of 16. W traffic: 64 MB L2 total, 256 KB/block spread over 256 CUs.
__global__ __launch_bounds__(1024) void proj_hidden_kernel(
    const float* __restrict__ hidden, const float* __restrict__ W,
    float* __restrict__ v)
{
    const int tx = threadIdx.x & 15;       // quad within block
    const int ty = threadIdx.x >> 4;       // 0..63, o-chunk of 16
    const int q  = blockIdx.x * 16 + tx;   // global float4 column 0..255
    const int b0 = blockIdx.y * 2;
    const float4* W4 = reinterpret_cast<const float4*>(W);
    const float* h0 = hidden + b0 * H;
    const float* h1 = h0 + H;

    float4 a0 = {0.f, 0.f, 0.f, 0.f}, a1 = {0.f, 0.f, 0.f, 0.f};
#pragma unroll
    for (int i = 0; i < 16; ++i) {
        const int o = ty * 16 + i;
        const float4 w = W4[(size_t)o * (H / 4) + q];
        const float s0 = h0[o], s1 = h1[o];
        a0.x += s0 * w.x; a0.y += s0 * w.y; a0.z += s0 * w.z; a0.w += s0 * w.w;
        a1.x += s1 * w.x; a1.y += s1 * w.y; a1.z += s1 * w.z; a1.w += s1 * w.w;
    }

    __shared__ float4 red[32][16][2];      // 16 KB
#pragma unroll
    for (int step = 32; step >= 1; step >>= 1) {
        if (ty >= step && ty < 2 * step) {
            red[ty - step][tx][0] = a0;
            red[ty - step][tx][1] = a1;
        }
        __syncthreads();
        if (ty < step) {
            const float4 r0 = red[ty][tx][0], r1 = red[ty][tx][1];
            a0.x += r0.x; a0.y += r0.y; a0.z += r0.z; a0.w += r0.w;
            a1.x += r1.x; a1.y += r1.y; a1.z += r1.z; a1.w += r1.w;
        }
        __syncthreads();
    }
    if (ty == 0) {
        reinterpret_cast<float4*>(v + (size_t)b0 * H)[q] = a0;
        reinterpret_cast<float4*>(v + (size_t)(b0 + 1) * H)[q] = a1;
    }
}

// Kernel B: energies[b,s] = dot(enc[s,b,:], v[b,:])
// One wave per 16 rows; per-lane partials for all 16 rows, then a 17-shuffle
// merge tree. enc loads are non-temporal (read-once stream, skip L2 caching);
// v loads stay cached.
__global__ __launch_bounds__(256) void energies_kernel(
    const float* __restrict__ enc, const float* __restrict__ v,
    float* __restrict__ e)
{
    const int lane = threadIdx.x & 63;
    const int wave = threadIdx.x >> 6;
    const int b = blockIdx.y;
    const int s_base = blockIdx.x * 64 + wave * 16;

    const float4* v4 = reinterpret_cast<const float4*>(v + b * H);
    float4 vr[4];
#pragma unroll
    for (int k = 0; k < 4; ++k) vr[k] = v4[k * 64 + lane];

    float acc[16];
#pragma unroll
    for (int r = 0; r < 16; ++r) {
        const f4* e4 = reinterpret_cast<const f4*>(
            enc + ((size_t)(s_base + r) * B + b) * H);
        float a = 0.f;
#pragma unroll
        for (int k = 0; k < 4; ++k) {
            const f4 x = __builtin_nontemporal_load(e4 + k * 64 + lane);
            a += x[0] * vr[k].x + x[1] * vr[k].y + x[2] * vr[k].z + x[3] * vr[k].w;
        }
        acc[r] = a;
    }

    float t[8];
#pragma unroll
    for (int j = 0; j < 8; ++j) {            // xor 1: 16 -> 8
        const float a = acc[2 * j], c = acc[2 * j + 1];
        const float send = (lane & 1) ? a : c;
        const float recv = __shfl_xor(send, 1, 64);
        t[j] = ((lane & 1) ? c : a) + recv;
    }
#pragma unroll
    for (int j = 0; j < 4; ++j) {            // xor 2: 8 -> 4
        const float a = t[2 * j], c = t[2 * j + 1];
        const float send = (lane & 2) ? a : c;
        const float recv = __shfl_xor(send, 2, 64);
        t[j] = ((lane & 2) ? c : a) + recv;
    }
#pragma unroll
    for (int j = 0; j < 2; ++j) {            // xor 4: 4 -> 2
        const float a = t[2 * j], c = t[2 * j + 1];
        const float send = (lane & 4) ? a : c;
        const float recv = __shfl_xor(send, 4, 64);
        t[j] = ((lane & 4) ? c : a) + recv;
    }
    {                                        // xor 8: 2 -> 1
        const float a = t[0], c = t[1];
        const float send = (lane & 8) ? a : c;
        const float recv = __shfl_xor(send, 8, 64);
        t[0] = ((lane & 8) ? c : a) + recv;
    }
    t[0] += __shfl_xor(t[0], 16, 64);
    t[0] += __shfl_xor(t[0], 32, 64);

    if (lane < 16)
        e[b * S + s_base + lane] = t[0];
}

// Kernel C: softmax over s per b. One block per b, 256 threads x 8 vals.
__global__ __launch_bounds__(256) void softmax_kernel(
    const float* __restrict__ e, float* __restrict__ out)
{
    const int b = blockIdx.x;
    const int tid = threadIdx.x;
    const int lane = tid & 63, wv = tid >> 6;

    float vals[8];
#pragma unroll
    for (int i = 0; i < 8; ++i) vals[i] = e[b * S + tid + i * 256];

    float m = vals[0];
#pragma unroll
    for (int i = 1; i < 8; ++i) m = fmaxf(m, vals[i]);
#pragma unroll
    for (int off = 32; off > 0; off >>= 1)
        m = fmaxf(m, __shfl_xor(m, off, 64));

    __shared__ float redm[4];
    __shared__ float reds[4];
    if (lane == 0) redm[wv] = m;
    __syncthreads();
    m = fmaxf(fmaxf(redm[0], redm[1]), fmaxf(redm[2], redm[3]));

    float sum = 0.f;
#pragma unroll
    for (int i = 0; i < 8; ++i) { vals[i] = __expf(vals[i] - m); sum += vals[i]; }
#pragma unroll
    for (int off = 32; off > 0; off >>= 1)
        sum += __shfl_xor(sum, off, 64);
    if (lane == 0) reds[wv] = sum;
    __syncthreads();
    sum = reds[0] + reds[1] + reds[2] + reds[3];

    const float inv = 1.f / sum;
#pragma unroll
    for (int i = 0; i < 8; ++i) out[b * S + tid + i * 256] = vals[i] * inv;
}

extern "C" void kernel_launch(void* const* d_in, const int* in_sizes, int n_in,
                              void* d_out, int out_size, void* d_ws, size_t ws_size,
                              hipStream_t stream) {
    const float* hidden = (const float*)d_in[0];   // [1,B,H]
    const float* enc    = (const float*)d_in[1];   // [S,B,H]
    const float* W      = (const float*)d_in[2];   // [H,H] (o,h)
    // d_in[3] bias: identically zero AND softmax-shift-invariant -> skipped.
    float* out = (float*)d_out;                    // [B,1,S]

    float* v = (float*)d_ws;                       // B*H floats = 128 KB
    float* e = v + B * H;                          // B*S floats = 256 KB

    proj_hidden_kernel<<<dim3(H / 64, B / 2), 1024, 0, stream>>>(hidden, W, v);
    energies_kernel<<<dim3(S / 64, B), 256, 0, stream>>>(enc, v, e);
    softmax_kernel<<<B, 256, 0, stream>>>(e, out);
}